// Round 4
// baseline (65.944 us; speedup 1.0000x reference)
//
#include <hip/hip_runtime.h>

#define BLOCK 256

// One thread per atom. Wave-private [64][29] LDS out-staging (no block
// barriers in loop). NEW: depth-1 software pipeline — tile t+1's mask+info
// loads are issued before tile t's compute/store, so ~900cy HBM latency
// hides under PROCESS. Two named register sets (static indexing, rule #20).
__global__ __launch_bounds__(BLOCK, 4) void efp_kernel(
    const float* __restrict__ info,   // [M,7]
    const float* __restrict__ mask,   // [M]
    const float* __restrict__ W,      // [16,5]  (uniform -> SGPR)
    const float* __restrict__ bias,   // [16]
    const float* __restrict__ atom,   // [95,8]
    const float* __restrict__ typ,    // [6,4]
    float* __restrict__ out,          // [M,28]
    int ntiles)
{
    __shared__ float4 s_atom[95 * 3];      // rows padded to 48B -> 8 bank groups
    __shared__ float4 s_typ[6];
    __shared__ float  s_out[4][64 * 29];   // per-wave; 29 coprime w/ 32 banks

    const int tid = threadIdx.x;
    const int wid = tid >> 6;
    const int lane = tid & 63;

    if (tid < 190) {
        const int a = tid >> 1, j = tid & 1;
        s_atom[a * 3 + j] = reinterpret_cast<const float4*>(atom)[tid];
    }
    if (tid < 6) s_typ[tid] = reinterpret_cast<const float4*>(typ)[tid];
    __syncthreads();                       // only block barrier

    float* const sw = s_out[wid];
    const int stride = gridDim.x;

    auto LOAD = [&](int tile, float& m, float* r) {
        const long long i = (long long)tile * BLOCK + wid * 64 + lane;
        m = mask[i];
        const float* gi = info + i * 7;
        #pragma unroll
        for (int k = 0; k < 7; ++k) r[k] = gi[k];
    };

    auto PROCESS = [&](int tile, float m, const float* r) {
        const long long abase = (long long)tile * BLOCK + wid * 64;
        // exact reference semantics
        const float f0 = r[0] * m, f1 = r[1] * m, f2 = r[2] * m,
                    f3 = r[3] * m, f4 = r[4] * m;
        const int an = (int)(r[5] * m);        // trunc toward zero
        const int et = (int)(r[6] * m);
        const bool active = (m >= 0.5f);
        const bool valid  = active && (an >= 1) && (an <= 94);
        const int anc = min(max(an, 0), 94);
        const int etc = min(max(et, 0), 5);
        const float sc_ff  = active ? m : 0.0f;
        const float sc_emb = valid  ? m : 0.0f;

        float* so = sw + lane * 29;
        #pragma unroll
        for (int o = 0; o < 16; ++o) {
            float acc = bias[o];
            acc = fmaf(W[o * 5 + 0], f0, acc);
            acc = fmaf(W[o * 5 + 1], f1, acc);
            acc = fmaf(W[o * 5 + 2], f2, acc);
            acc = fmaf(W[o * 5 + 3], f3, acc);
            acc = fmaf(W[o * 5 + 4], f4, acc);
            so[o] = fmaxf(acc, 0.0f) * sc_ff;
        }
        const float4 a0 = s_atom[anc * 3 + 0];
        const float4 a1 = s_atom[anc * 3 + 1];
        const float4 t0 = s_typ[etc];
        so[16] = a0.x * sc_emb;  so[17] = a0.y * sc_emb;
        so[18] = a0.z * sc_emb;  so[19] = a0.w * sc_emb;
        so[20] = a1.x * sc_emb;  so[21] = a1.y * sc_emb;
        so[22] = a1.z * sc_emb;  so[23] = a1.w * sc_emb;
        so[24] = t0.x * sc_emb;  so[25] = t0.y * sc_emb;
        so[26] = t0.z * sc_emb;  so[27] = t0.w * sc_emb;

        // intra-wave fence: ds_writes visible before cross-lane ds_reads
        asm volatile("s_waitcnt lgkmcnt(0)" ::: "memory");
        __builtin_amdgcn_sched_barrier(0);

        float4* go = reinterpret_cast<float4*>(out) + abase * 7;
        #pragma unroll
        for (int k = 0; k < 7; ++k) {
            const int l = k * 64 + lane;       // 0..447
            const int row = l / 7;
            const int col = (l - row * 7) * 4;
            const float* sr = sw + row * 29 + col;
            go[l] = make_float4(sr[0], sr[1], sr[2], sr[3]);
        }

        // WAR fence: next tile's ds_writes stay below this tile's ds_reads
        asm volatile("" ::: "memory");
        __builtin_amdgcn_sched_barrier(0);
    };

    int t = blockIdx.x;
    float ma, ra[7];
    float mb, rb[7];
    LOAD(t, ma, ra);                           // prime the pipeline
    for (; t < ntiles; t += 2 * stride) {
        const int t1 = t + stride;
        if (t1 < ntiles) LOAD(t1, mb, rb);     // prefetch (uniform branch)
        PROCESS(t, ma, ra);
        const int t2 = t + 2 * stride;
        if (t2 < ntiles) LOAD(t2, ma, ra);     // prefetch
        if (t1 < ntiles) PROCESS(t1, mb, rb);
    }
}

extern "C" void kernel_launch(void* const* d_in, const int* in_sizes, int n_in,
                              void* d_out, int out_size, void* d_ws, size_t ws_size,
                              hipStream_t stream) {
    const float* info = (const float*)d_in[0];
    const float* mask = (const float*)d_in[1];
    const float* W    = (const float*)d_in[2];
    const float* bias = (const float*)d_in[3];
    const float* atom = (const float*)d_in[4];
    const float* typ  = (const float*)d_in[5];
    float* out = (float*)d_out;

    const int M = in_sizes[1];           // B*N, divisible by 256
    const int ntiles = M / BLOCK;
    int grid = ntiles < 2048 ? ntiles : 2048;

    hipLaunchKernelGGL(efp_kernel, dim3(grid), dim3(BLOCK), 0, stream,
                       info, mask, W, bias, atom, typ, out, ntiles);
}